// Round 2
// baseline (420.921 us; speedup 1.0000x reference)
//
#include <hip/hip_runtime.h>
#include <hip/hip_bf16.h>

#define N_NODES 50000
#define N_EDGES 1600000
#define F_IN    512
#define F_HID   128
#define F_OUT   64
#define NBUK    391          // ceil(50000/128) buckets of 128 nodes
#define EPB     8192         // edges per block in bucket passes
#define CAP     4864         // per-bucket slot capacity (mean 4092, +12 sigma)

typedef short bf16x8 __attribute__((ext_vector_type(8)));
typedef float f32x4  __attribute__((ext_vector_type(4)));

__device__ __forceinline__ short f32_to_bf16(float f) {
    unsigned u = __float_as_uint(f);
    u += 0x7FFF + ((u >> 16) & 1);          // RTNE
    return (short)(u >> 16);
}
__device__ __forceinline__ float bf16_to_f32(short s) {
    return __uint_as_float(((unsigned)(unsigned short)s) << 16);
}
__device__ __forceinline__ float bf16lo(unsigned u) { return __uint_as_float(u << 16); }
__device__ __forceinline__ float bf16hi(unsigned u) { return __uint_as_float(u & 0xFFFF0000u); }

// ---------------- CSR build: bucket partition with fixed-capacity slots ----------------

// partition edges into bucket slots (records: (dst<<16|src, w)); self-reserving cursors
__global__ __launch_bounds__(256) void part_a(const int* __restrict__ dst,
                                              const int* __restrict__ src,
                                              const float* __restrict__ w,
                                              int* __restrict__ gcnt,
                                              uint2* __restrict__ tmp, int E) {
    __shared__ int h[NBUK];
    __shared__ int base[NBUK];
    for (int i = threadIdx.x; i < NBUK; i += 256) h[i] = 0;
    __syncthreads();
    int e0 = blockIdx.x * EPB;
    int e1 = min(e0 + EPB, E);
    for (int e = e0 + threadIdx.x; e < e1; e += 256)
        atomicAdd(&h[dst[e] >> 7], 1);
    __syncthreads();
    for (int i = threadIdx.x; i < NBUK; i += 256) {
        int c = h[i];
        base[i] = c ? atomicAdd(&gcnt[i], c) : 0;
        h[i] = 0;
    }
    __syncthreads();
    for (int e = e0 + threadIdx.x; e < e1; e += 256) {
        int d = dst[e];
        int b = d >> 7;
        int off = base[b] + atomicAdd(&h[b], 1);
        if (off < CAP)
            tmp[(size_t)b * CAP + off] = make_uint2(((unsigned)d << 16) | (unsigned)src[e],
                                                    __float_as_uint(w[e]));
    }
}

// per-bucket: node histogram + prefix in LDS -> rowinfo(beg,end), bucket-local scatter
__global__ __launch_bounds__(256) void part_b(const uint2* __restrict__ tmp,
                                              const int* __restrict__ gcnt,
                                              int2* __restrict__ rowinfo,
                                              uint2* __restrict__ erec) {
    __shared__ int s[128];
    __shared__ int cur[128];
    int b = blockIdx.x, tid = threadIdx.x;
    int nb0 = b << 7;
    int r0 = b * CAP;
    int cnt_b = min(gcnt[b], CAP);
    int r1 = r0 + cnt_b;
    if (tid < 128) s[tid] = 0;
    __syncthreads();
    for (int i = r0 + tid; i < r1; i += 256)
        atomicAdd(&s[(tmp[i].x >> 16) - nb0], 1);
    __syncthreads();
    int v = (tid < 128) ? s[tid] : 0;
    #pragma unroll
    for (int off = 1; off < 128; off <<= 1) {
        int t = (tid >= off && tid < 128) ? s[tid - off] : 0;
        __syncthreads();
        if (tid < 128) s[tid] += t;
        __syncthreads();
    }
    if (tid < 128) {
        int ex = r0 + s[tid] - v;
        cur[tid] = ex;
        int node = nb0 + tid;
        if (node < N_NODES) rowinfo[node] = make_int2(ex, ex + v);
    }
    __syncthreads();
    for (int i = r0 + tid; i < r1; i += 256) {
        uint2 rec = tmp[i];
        int p = atomicAdd(&cur[(rec.x >> 16) - nb0], 1);
        erec[p] = make_uint2(rec.x & 0xFFFFu, rec.y);
    }
}

// ---------------- fragment-order conversions ----------------
// A fragment unit u = (tile*KC + kc)*64 + lane  (16 B = bf16x8):
//   holds A[row = tile*16 + (lane&15)][k = kc*32 + (lane>>4)*8 .. +8]

template<int KD>
__global__ __launch_bounds__(256) void cvt_frag(const float* __restrict__ X,
                                                bf16x8* __restrict__ Afrag, int n_units) {
    constexpr int KC = KD / 32;
    int u = blockIdx.x * 256 + threadIdx.x;
    if (u >= n_units) return;
    int lane = u & 63;
    int kc   = (u >> 6) & (KC - 1);
    int tile = u / (64 * KC);
    int row  = tile * 16 + (lane & 15);
    int k    = kc * 32 + (lane >> 4) * 8;
    const float* p = X + (size_t)row * KD + k;
    float4 a0 = *(const float4*)p;
    float4 a1 = *(const float4*)(p + 4);
    bf16x8 f;
    f[0] = f32_to_bf16(a0.x); f[1] = f32_to_bf16(a0.y);
    f[2] = f32_to_bf16(a0.z); f[3] = f32_to_bf16(a0.w);
    f[4] = f32_to_bf16(a1.x); f[5] = f32_to_bf16(a1.y);
    f[6] = f32_to_bf16(a1.z); f[7] = f32_to_bf16(a1.w);
    Afrag[u] = f;
}

// B fragment unit u = (kc*NT + nt)*64 + lane:
//   holds W[k = kc*32 + (lane>>4)*8 + j][n = nt*16 + (lane&15)]  (W is [KD][NC] row-major)
template<int KD, int NC>
__global__ void wtrans_frag(const float* __restrict__ W, bf16x8* __restrict__ Bfrag) {
    constexpr int KC = KD / 32, NT = NC / 16;
    int u = blockIdx.x * 256 + threadIdx.x;
    if (u >= KC * NT * 64) return;
    int lane = u & 63;
    int nt   = (u >> 6) % NT;
    int kc   = u / (64 * NT);
    int n = nt * 16 + (lane & 15);
    int k = kc * 32 + (lane >> 4) * 8;
    bf16x8 f;
    #pragma unroll
    for (int j = 0; j < 8; ++j) f[j] = f32_to_bf16(W[(size_t)(k + j) * NC + n]);
    Bfrag[u] = f;
}

// ---------------- fragment MFMA GEMM: C[M,NC](bf16) ----------------

template<int NC, int KD>
__global__ __launch_bounds__(256) void mfma_gemm_frag(const bf16x8* __restrict__ Afrag,
                                                      const bf16x8* __restrict__ Bfrag,
                                                      short* __restrict__ C, int Mt) {
    constexpr int NT = NC / 16, KC = KD / 32;
    constexpr int PFA = (KC < 4) ? KC : 4;
    const int lane = threadIdx.x & 63;
    const int wave = threadIdx.x >> 6;
    const int tile = blockIdx.x * 4 + wave;
    if (tile >= Mt) return;

    const bf16x8* ap = Afrag + (size_t)tile * KC * 64 + lane;
    const bf16x8* bp = Bfrag + lane;

    f32x4 acc[NT];
    #pragma unroll
    for (int i = 0; i < NT; ++i) acc[i] = (f32x4){0.f, 0.f, 0.f, 0.f};

    bf16x8 abuf[PFA];
    #pragma unroll
    for (int i = 0; i < PFA; ++i) abuf[i] = ap[(size_t)i * 64];
    bf16x8 bbuf[NT];
    #pragma unroll
    for (int nt = 0; nt < NT; ++nt) bbuf[nt] = bp[(size_t)nt * 64];

    #pragma unroll
    for (int kc = 0; kc < KC; ++kc) {
        bf16x8 a = abuf[kc % PFA];
        int ka = kc + PFA; if (ka > KC - 1) ka = KC - 1;
        abuf[kc % PFA] = ap[(size_t)ka * 64];
        int kb = (kc + 1 < KC) ? kc + 1 : kc;
        bf16x8 bnew[NT];
        #pragma unroll
        for (int nt = 0; nt < NT; ++nt) {
            bnew[nt] = bp[((size_t)kb * NT + nt) * 64];
            acc[nt] = __builtin_amdgcn_mfma_f32_16x16x32_bf16(a, bbuf[nt], acc[nt], 0, 0, 0);
        }
        #pragma unroll
        for (int nt = 0; nt < NT; ++nt) bbuf[nt] = bnew[nt];
    }

    const int lrow = lane & 15, kgrp = lane >> 4;
    #pragma unroll
    for (int nt = 0; nt < NT; ++nt) {
        #pragma unroll
        for (int r = 0; r < 4; ++r) {
            int grow = tile * 16 + kgrp * 4 + r;
            C[(size_t)grow * NC + nt * 16 + lrow] = f32_to_bf16(acc[nt][r]);
        }
    }
}

// ---------------- SpMM gather ----------------

// F=128: one WAVE per node, 4 nodes per 256-thread block (32 waves/CU capacity).
// 8-wide masked unroll: 8 erec loads + 8 feat gathers in flight, no serial tail.
// lane t owns feats (2t, 2t+1); frag uint slot:
//   unit = (tile*4 + t/16)*64 + ((t>>2)&3)*16 + (d&15), uint index = unit*4 + (t&3)
__global__ __launch_bounds__(256, 8) void spmm128(const int2* __restrict__ rowinfo,
                                                  const uint2* __restrict__ erec,
                                                  const unsigned* __restrict__ featu,
                                                  const float* __restrict__ bias,
                                                  float* __restrict__ out,
                                                  unsigned* __restrict__ afrag2u) {
    const int wid = threadIdx.x >> 6;
    const int t   = threadIdx.x & 63;
    const int d   = blockIdx.x * 4 + wid;           // grid 12500 * 4 = 50000 exact
    int2 ri = rowinfo[d];
    int beg = ri.x, end = ri.y;
    float a0 = 0.f, a1 = 0.f;
    const unsigned* fp = featu + t;
    for (int e = beg; e < end; e += 8) {
        uint2 r[8];
        #pragma unroll
        for (int j = 0; j < 8; ++j) {
            int idx = e + j;
            r[j] = erec[idx < end ? idx : beg];     // clamp: always-valid address
            if (idx >= end) r[j].y = 0u;            // masked lanes contribute 0
        }
        unsigned f[8];
        #pragma unroll
        for (int j = 0; j < 8; ++j) f[j] = fp[(size_t)r[j].x * 64];
        #pragma unroll
        for (int j = 0; j < 8; ++j) {
            float w = __uint_as_float(r[j].y);
            a0 += w * bf16lo(f[j]);
            a1 += w * bf16hi(f[j]);
        }
    }
    float2 bv = *(const float2*)&bias[2 * t];
    float ox = fmaxf(a0 + bv.x, 0.f);
    float oy = fmaxf(a1 + bv.y, 0.f);
    *(float2*)&out[(size_t)d * 128 + 2 * t] = make_float2(ox, oy);
    unsigned packed = (unsigned)(unsigned short)f32_to_bf16(ox) |
                      ((unsigned)(unsigned short)f32_to_bf16(oy) << 16);
    int unit = ((d >> 4) * 4 + (t >> 4)) * 64 + ((t >> 2) & 3) * 16 + (d & 15);
    afrag2u[unit * 4 + (t & 3)] = packed;
}

// F=64: one wave per node, 4 nodes per block, 8-wide masked unroll.
__global__ __launch_bounds__(256, 8) void spmm64(const int2* __restrict__ rowinfo,
                                                 const uint2* __restrict__ erec,
                                                 const short* __restrict__ feat,
                                                 const float* __restrict__ bias,
                                                 float* __restrict__ out) {
    const int wid = threadIdx.x >> 6;
    const int t   = threadIdx.x & 63;
    const int d   = blockIdx.x * 4 + wid;
    int2 ri = rowinfo[d];
    int beg = ri.x, end = ri.y;
    float acc = 0.f;
    const short* fp = feat + t;
    for (int e = beg; e < end; e += 8) {
        uint2 r[8];
        #pragma unroll
        for (int j = 0; j < 8; ++j) {
            int idx = e + j;
            r[j] = erec[idx < end ? idx : beg];
            if (idx >= end) r[j].y = 0u;
        }
        float f[8];
        #pragma unroll
        for (int j = 0; j < 8; ++j) f[j] = bf16_to_f32(fp[(size_t)r[j].x * 64]);
        #pragma unroll
        for (int j = 0; j < 8; ++j) acc += __uint_as_float(r[j].y) * f[j];
    }
    out[(size_t)d * 64 + t] = acc + bias[t];
}

// ---------------- launch ----------------

extern "C" void kernel_launch(void* const* d_in, const int* in_sizes, int n_in,
                              void* d_out, int out_size, void* d_ws, size_t ws_size,
                              hipStream_t stream) {
    const float* x  = (const float*)d_in[0];
    const int*   ei = (const int*)d_in[1];
    const float* ew = (const float*)d_in[2];
    const float* W1 = (const float*)d_in[3];
    const float* b1 = (const float*)d_in[4];
    const float* W2 = (const float*)d_in[5];
    const float* b2 = (const float*)d_in[6];

    const int* dst = ei;
    const int* src = ei + N_EDGES;

    float* x1 = (float*)d_out;                          // [50000,128] fp32
    float* x2 = x1 + (size_t)N_NODES * F_HID;           // [50000,64]  fp32

    char* ws = (char*)d_ws;
    uint2*  erec     = (uint2*)ws;  ws += (size_t)NBUK * CAP * 8;         // 15.2 MB (slotted)
    uint2*  tmp      = (uint2*)ws;  ws += (size_t)NBUK * CAP * 8;         // 15.2 MB (slotted)
    short*  support1 = (short*)ws;  ws += (size_t)N_NODES * F_HID * 2;    // 12.8 MB
    short*  support2 = (short*)ws;  ws += (size_t)N_NODES * F_OUT * 2;    //  6.4 MB
    bf16x8* Afrag1   = (bf16x8*)ws; ws += (size_t)N_NODES * F_IN * 2;     // 51.2 MB
    bf16x8* Afrag2   = (bf16x8*)ws; ws += (size_t)N_NODES * F_HID * 2;    // 12.8 MB
    bf16x8* Bfrag1   = (bf16x8*)ws; ws += (size_t)F_HID * F_IN * 2;       //  128 KB
    bf16x8* Bfrag2   = (bf16x8*)ws; ws += (size_t)F_OUT * F_HID * 2;      //   16 KB
    int2*   rowinfo  = (int2*)ws;   ws += (size_t)N_NODES * 8;            //  400 KB
    int*    gcnt     = (int*)ws;    ws += 400 * 4;

    const int NPB = (N_EDGES + EPB - 1) / EPB;          // 196 partition blocks
    const int MT  = N_NODES / 16;                       // 3125 row tiles (exact)

    // 0) x -> fragment-order bf16 (independent of CSR build)
    {
        int n_units = MT * (F_IN / 32) * 64;            // 3.2M
        cvt_frag<F_IN><<<(n_units + 255) / 256, 256, 0, stream>>>(x, Afrag1, n_units);
    }

    // 1) CSR build (bucket partition, self-reserving fixed-capacity slots)
    hipMemsetAsync(gcnt, 0, NBUK * sizeof(int), stream);
    part_a<<<NPB, 256, 0, stream>>>(dst, src, ew, gcnt, tmp, N_EDGES);
    part_b<<<NBUK, 256, 0, stream>>>(tmp, gcnt, rowinfo, erec);

    // 2) weight prep (fragment-order bf16)
    wtrans_frag<F_IN, F_HID><<<32, 256, 0, stream>>>(W1, Bfrag1);
    wtrans_frag<F_HID, F_OUT><<<4, 256, 0, stream>>>(W2, Bfrag2);

    // 3) support1 = x @ W1 (bf16 out)
    mfma_gemm_frag<F_HID, F_IN><<<(MT + 3) / 4, 256, 0, stream>>>(Afrag1, Bfrag1, support1, MT);

    // 4) x1 = relu(spmm(support1) + b1); also emits Afrag2 (bf16 fragment order)
    spmm128<<<N_NODES / 4, 256, 0, stream>>>(rowinfo, erec, (const unsigned*)support1, b1, x1,
                                             (unsigned*)Afrag2);

    // 5) support2 = x1 @ W2 (bf16 out)
    mfma_gemm_frag<F_OUT, F_HID><<<(MT + 3) / 4, 256, 0, stream>>>(Afrag2, Bfrag2, support2, MT);

    // 6) x2 = spmm(support2) + b2
    spmm64<<<N_NODES / 4, 256, 0, stream>>>(rowinfo, erec, support2, b2, x2);
}

// Round 3
// 362.348 us; speedup vs baseline: 1.1616x; 1.1616x over previous
//
#include <hip/hip_runtime.h>
#include <hip/hip_bf16.h>

#define N_NODES 50000
#define N_EDGES 1600000
#define F_IN    512
#define F_HID   128
#define F_OUT   64
#define NBUK    391          // ceil(50000/128) buckets of 128 nodes
#define EPB     8192         // edges per block in bucket passes
#define CAP     4864         // per-bucket slot capacity (mean 4092, +12 sigma)

typedef short bf16x8 __attribute__((ext_vector_type(8)));
typedef float f32x4  __attribute__((ext_vector_type(4)));

__device__ __forceinline__ short f32_to_bf16(float f) {
    unsigned u = __float_as_uint(f);
    u += 0x7FFF + ((u >> 16) & 1);          // RTNE
    return (short)(u >> 16);
}
__device__ __forceinline__ float bf16_to_f32(short s) {
    return __uint_as_float(((unsigned)(unsigned short)s) << 16);
}
__device__ __forceinline__ float bf16lo(unsigned u) { return __uint_as_float(u << 16); }
__device__ __forceinline__ float bf16hi(unsigned u) { return __uint_as_float(u & 0xFFFF0000u); }

// ---------------- CSR build: bucket partition with fixed-capacity slots ----------------

// partition edges into bucket slots (records: (dst<<16|src, w)); self-reserving cursors
__global__ __launch_bounds__(256) void part_a(const int* __restrict__ dst,
                                              const int* __restrict__ src,
                                              const float* __restrict__ w,
                                              int* __restrict__ gcnt,
                                              uint2* __restrict__ tmp, int E) {
    __shared__ int h[NBUK];
    __shared__ int base[NBUK];
    for (int i = threadIdx.x; i < NBUK; i += 256) h[i] = 0;
    __syncthreads();
    int e0 = blockIdx.x * EPB;
    int e1 = min(e0 + EPB, E);
    for (int e = e0 + threadIdx.x; e < e1; e += 256)
        atomicAdd(&h[dst[e] >> 7], 1);
    __syncthreads();
    for (int i = threadIdx.x; i < NBUK; i += 256) {
        int c = h[i];
        base[i] = c ? atomicAdd(&gcnt[i], c) : 0;
        h[i] = 0;
    }
    __syncthreads();
    for (int e = e0 + threadIdx.x; e < e1; e += 256) {
        int d = dst[e];
        int b = d >> 7;
        int off = base[b] + atomicAdd(&h[b], 1);
        if (off < CAP)
            tmp[(size_t)b * CAP + off] = make_uint2(((unsigned)d << 16) | (unsigned)src[e],
                                                    __float_as_uint(w[e]));
    }
}

// per-bucket: node histogram + prefix in LDS -> rowinfo(beg,end), bucket-local scatter
__global__ __launch_bounds__(256) void part_b(const uint2* __restrict__ tmp,
                                              const int* __restrict__ gcnt,
                                              int2* __restrict__ rowinfo,
                                              uint2* __restrict__ erec) {
    __shared__ int s[128];
    __shared__ int cur[128];
    int b = blockIdx.x, tid = threadIdx.x;
    int nb0 = b << 7;
    int r0 = b * CAP;
    int cnt_b = min(gcnt[b], CAP);
    int r1 = r0 + cnt_b;
    if (tid < 128) s[tid] = 0;
    __syncthreads();
    for (int i = r0 + tid; i < r1; i += 256)
        atomicAdd(&s[(tmp[i].x >> 16) - nb0], 1);
    __syncthreads();
    int v = (tid < 128) ? s[tid] : 0;
    #pragma unroll
    for (int off = 1; off < 128; off <<= 1) {
        int t = (tid >= off && tid < 128) ? s[tid - off] : 0;
        __syncthreads();
        if (tid < 128) s[tid] += t;
        __syncthreads();
    }
    if (tid < 128) {
        int ex = r0 + s[tid] - v;
        cur[tid] = ex;
        int node = nb0 + tid;
        if (node < N_NODES) rowinfo[node] = make_int2(ex, ex + v);
    }
    __syncthreads();
    for (int i = r0 + tid; i < r1; i += 256) {
        uint2 rec = tmp[i];
        int p = atomicAdd(&cur[(rec.x >> 16) - nb0], 1);
        erec[p] = make_uint2(rec.x & 0xFFFFu, rec.y);
    }
}

// ---------------- fragment-order conversions ----------------
// A fragment unit u = (tile*KC + kc)*64 + lane  (16 B = bf16x8):
//   holds A[row = tile*16 + (lane&15)][k = kc*32 + (lane>>4)*8 .. +8]

template<int KD>
__global__ __launch_bounds__(256) void cvt_frag(const float* __restrict__ X,
                                                bf16x8* __restrict__ Afrag, int n_units) {
    constexpr int KC = KD / 32;
    int u = blockIdx.x * 256 + threadIdx.x;
    if (u >= n_units) return;
    int lane = u & 63;
    int kc   = (u >> 6) & (KC - 1);
    int tile = u / (64 * KC);
    int row  = tile * 16 + (lane & 15);
    int k    = kc * 32 + (lane >> 4) * 8;
    const float* p = X + (size_t)row * KD + k;
    float4 a0 = *(const float4*)p;
    float4 a1 = *(const float4*)(p + 4);
    bf16x8 f;
    f[0] = f32_to_bf16(a0.x); f[1] = f32_to_bf16(a0.y);
    f[2] = f32_to_bf16(a0.z); f[3] = f32_to_bf16(a0.w);
    f[4] = f32_to_bf16(a1.x); f[5] = f32_to_bf16(a1.y);
    f[6] = f32_to_bf16(a1.z); f[7] = f32_to_bf16(a1.w);
    Afrag[u] = f;
}

// B fragment unit u = (kc*NT + nt)*64 + lane:
//   holds W[k = kc*32 + (lane>>4)*8 + j][n = nt*16 + (lane&15)]  (W is [KD][NC] row-major)
template<int KD, int NC>
__global__ void wtrans_frag(const float* __restrict__ W, bf16x8* __restrict__ Bfrag) {
    constexpr int KC = KD / 32, NT = NC / 16;
    int u = blockIdx.x * 256 + threadIdx.x;
    if (u >= KC * NT * 64) return;
    int lane = u & 63;
    int nt   = (u >> 6) % NT;
    int kc   = u / (64 * NT);
    int n = nt * 16 + (lane & 15);
    int k = kc * 32 + (lane >> 4) * 8;
    bf16x8 f;
    #pragma unroll
    for (int j = 0; j < 8; ++j) f[j] = f32_to_bf16(W[(size_t)(k + j) * NC + n]);
    Bfrag[u] = f;
}

// ---------------- fragment MFMA GEMM: C[M,NC](bf16) ----------------

template<int NC, int KD>
__global__ __launch_bounds__(256) void mfma_gemm_frag(const bf16x8* __restrict__ Afrag,
                                                      const bf16x8* __restrict__ Bfrag,
                                                      short* __restrict__ C, int Mt) {
    constexpr int NT = NC / 16, KC = KD / 32;
    constexpr int PFA = (KC < 4) ? KC : 4;
    const int lane = threadIdx.x & 63;
    const int wave = threadIdx.x >> 6;
    const int tile = blockIdx.x * 4 + wave;
    if (tile >= Mt) return;

    const bf16x8* ap = Afrag + (size_t)tile * KC * 64 + lane;
    const bf16x8* bp = Bfrag + lane;

    f32x4 acc[NT];
    #pragma unroll
    for (int i = 0; i < NT; ++i) acc[i] = (f32x4){0.f, 0.f, 0.f, 0.f};

    bf16x8 abuf[PFA];
    #pragma unroll
    for (int i = 0; i < PFA; ++i) abuf[i] = ap[(size_t)i * 64];
    bf16x8 bbuf[NT];
    #pragma unroll
    for (int nt = 0; nt < NT; ++nt) bbuf[nt] = bp[(size_t)nt * 64];

    #pragma unroll
    for (int kc = 0; kc < KC; ++kc) {
        bf16x8 a = abuf[kc % PFA];
        int ka = kc + PFA; if (ka > KC - 1) ka = KC - 1;
        abuf[kc % PFA] = ap[(size_t)ka * 64];
        int kb = (kc + 1 < KC) ? kc + 1 : kc;
        bf16x8 bnew[NT];
        #pragma unroll
        for (int nt = 0; nt < NT; ++nt) {
            bnew[nt] = bp[((size_t)kb * NT + nt) * 64];
            acc[nt] = __builtin_amdgcn_mfma_f32_16x16x32_bf16(a, bbuf[nt], acc[nt], 0, 0, 0);
        }
        #pragma unroll
        for (int nt = 0; nt < NT; ++nt) bbuf[nt] = bnew[nt];
    }

    const int lrow = lane & 15, kgrp = lane >> 4;
    #pragma unroll
    for (int nt = 0; nt < NT; ++nt) {
        #pragma unroll
        for (int r = 0; r < 4; ++r) {
            int grow = tile * 16 + kgrp * 4 + r;
            C[(size_t)grow * NC + nt * 16 + lrow] = f32_to_bf16(acc[nt][r]);
        }
    }
}

// ---------------- SpMM gather ----------------

// F=128: one wave per node (64-thd blocks — round-0 known-good shape).
// 8-wide UNMASKED main loop, software-pipelined: erec batch for iteration i+1
// issues while iteration i's feat gathers are in flight -> erec latency off the
// serial path. Tails: 4-wide then scalar (no per-edge compares anywhere).
// lane t owns feats (2t, 2t+1); frag uint slot:
//   unit = (tile*4 + t/16)*64 + ((t>>2)&3)*16 + (d&15), uint index = unit*4 + (t&3)
__global__ __launch_bounds__(64) void spmm128(const int2* __restrict__ rowinfo,
                                              const uint2* __restrict__ erec,
                                              const unsigned* __restrict__ featu,
                                              const float* __restrict__ bias,
                                              float* __restrict__ out,
                                              unsigned* __restrict__ afrag2u) {
    int d = blockIdx.x, tid = threadIdx.x;
    int2 ri = rowinfo[d];
    int beg = ri.x, end = ri.y;
    float a0 = 0.f, a1 = 0.f;
    const unsigned* fp = featu + tid;
    int e = beg;
    if (end - beg >= 8) {
        uint2 r[8];
        #pragma unroll
        for (int j = 0; j < 8; ++j) r[j] = erec[e + j];
        for (; e + 16 <= end; e += 8) {
            unsigned f[8];
            #pragma unroll
            for (int j = 0; j < 8; ++j) f[j] = fp[r[j].x * 64u];
            uint2 rn[8];
            #pragma unroll
            for (int j = 0; j < 8; ++j) rn[j] = erec[e + 8 + j];
            #pragma unroll
            for (int j = 0; j < 8; ++j) {
                float w = __uint_as_float(r[j].y);
                a0 += w * bf16lo(f[j]);
                a1 += w * bf16hi(f[j]);
            }
            #pragma unroll
            for (int j = 0; j < 8; ++j) r[j] = rn[j];
        }
        {   // drain: last full batch, no prefetch
            unsigned f[8];
            #pragma unroll
            for (int j = 0; j < 8; ++j) f[j] = fp[r[j].x * 64u];
            #pragma unroll
            for (int j = 0; j < 8; ++j) {
                float w = __uint_as_float(r[j].y);
                a0 += w * bf16lo(f[j]);
                a1 += w * bf16hi(f[j]);
            }
            e += 8;
        }
    }
    for (; e + 4 <= end; e += 4) {
        uint2 r0 = erec[e], r1 = erec[e + 1], r2 = erec[e + 2], r3 = erec[e + 3];
        unsigned f0 = fp[r0.x * 64u];
        unsigned f1 = fp[r1.x * 64u];
        unsigned f2 = fp[r2.x * 64u];
        unsigned f3 = fp[r3.x * 64u];
        float w0 = __uint_as_float(r0.y), w1 = __uint_as_float(r1.y);
        float w2 = __uint_as_float(r2.y), w3 = __uint_as_float(r3.y);
        a0 += w0 * bf16lo(f0); a1 += w0 * bf16hi(f0);
        a0 += w1 * bf16lo(f1); a1 += w1 * bf16hi(f1);
        a0 += w2 * bf16lo(f2); a1 += w2 * bf16hi(f2);
        a0 += w3 * bf16lo(f3); a1 += w3 * bf16hi(f3);
    }
    for (; e < end; ++e) {
        uint2 r = erec[e];
        unsigned f = fp[r.x * 64u];
        float w = __uint_as_float(r.y);
        a0 += w * bf16lo(f); a1 += w * bf16hi(f);
    }
    float ox = fmaxf(a0 + bias[2 * tid], 0.f);
    float oy = fmaxf(a1 + bias[2 * tid + 1], 0.f);
    *(float2*)&out[(size_t)d * 128 + 2 * tid] = make_float2(ox, oy);
    unsigned packed = (unsigned)(unsigned short)f32_to_bf16(ox) |
                      ((unsigned)(unsigned short)f32_to_bf16(oy) << 16);
    int unit = ((d >> 4) * 4 + (tid >> 4)) * 64 + ((tid >> 2) & 3) * 16 + (d & 15);
    afrag2u[unit * 4 + (tid & 3)] = packed;
}

// F=64: one wave per node, same pipelined 8-wide structure.
__global__ __launch_bounds__(64) void spmm64(const int2* __restrict__ rowinfo,
                                             const uint2* __restrict__ erec,
                                             const short* __restrict__ feat,
                                             const float* __restrict__ bias,
                                             float* __restrict__ out) {
    int d = blockIdx.x, tid = threadIdx.x;
    int2 ri = rowinfo[d];
    int beg = ri.x, end = ri.y;
    float acc = 0.f;
    const short* fp = feat + tid;
    int e = beg;
    if (end - beg >= 8) {
        uint2 r[8];
        #pragma unroll
        for (int j = 0; j < 8; ++j) r[j] = erec[e + j];
        for (; e + 16 <= end; e += 8) {
            float f[8];
            #pragma unroll
            for (int j = 0; j < 8; ++j) f[j] = bf16_to_f32(fp[r[j].x * 64u]);
            uint2 rn[8];
            #pragma unroll
            for (int j = 0; j < 8; ++j) rn[j] = erec[e + 8 + j];
            #pragma unroll
            for (int j = 0; j < 8; ++j) acc += __uint_as_float(r[j].y) * f[j];
            #pragma unroll
            for (int j = 0; j < 8; ++j) r[j] = rn[j];
        }
        {
            float f[8];
            #pragma unroll
            for (int j = 0; j < 8; ++j) f[j] = bf16_to_f32(fp[r[j].x * 64u]);
            #pragma unroll
            for (int j = 0; j < 8; ++j) acc += __uint_as_float(r[j].y) * f[j];
            e += 8;
        }
    }
    for (; e + 4 <= end; e += 4) {
        uint2 r0 = erec[e], r1 = erec[e + 1], r2 = erec[e + 2], r3 = erec[e + 3];
        float f0 = bf16_to_f32(fp[r0.x * 64u]);
        float f1 = bf16_to_f32(fp[r1.x * 64u]);
        float f2 = bf16_to_f32(fp[r2.x * 64u]);
        float f3 = bf16_to_f32(fp[r3.x * 64u]);
        acc += __uint_as_float(r0.y) * f0;
        acc += __uint_as_float(r1.y) * f1;
        acc += __uint_as_float(r2.y) * f2;
        acc += __uint_as_float(r3.y) * f3;
    }
    for (; e < end; ++e) {
        uint2 r = erec[e];
        acc += __uint_as_float(r.y) * bf16_to_f32(fp[r.x * 64u]);
    }
    out[(size_t)d * 64 + tid] = acc + bias[tid];
}

// ---------------- launch ----------------

extern "C" void kernel_launch(void* const* d_in, const int* in_sizes, int n_in,
                              void* d_out, int out_size, void* d_ws, size_t ws_size,
                              hipStream_t stream) {
    const float* x  = (const float*)d_in[0];
    const int*   ei = (const int*)d_in[1];
    const float* ew = (const float*)d_in[2];
    const float* W1 = (const float*)d_in[3];
    const float* b1 = (const float*)d_in[4];
    const float* W2 = (const float*)d_in[5];
    const float* b2 = (const float*)d_in[6];

    const int* dst = ei;
    const int* src = ei + N_EDGES;

    float* x1 = (float*)d_out;                          // [50000,128] fp32
    float* x2 = x1 + (size_t)N_NODES * F_HID;           // [50000,64]  fp32

    char* ws = (char*)d_ws;
    uint2*  erec     = (uint2*)ws;  ws += (size_t)NBUK * CAP * 8;         // 15.2 MB (slotted)
    uint2*  tmp      = (uint2*)ws;  ws += (size_t)NBUK * CAP * 8;         // 15.2 MB (slotted)
    short*  support1 = (short*)ws;  ws += (size_t)N_NODES * F_HID * 2;    // 12.8 MB
    short*  support2 = (short*)ws;  ws += (size_t)N_NODES * F_OUT * 2;    //  6.4 MB
    bf16x8* Afrag1   = (bf16x8*)ws; ws += (size_t)N_NODES * F_IN * 2;     // 51.2 MB
    bf16x8* Afrag2   = (bf16x8*)ws; ws += (size_t)N_NODES * F_HID * 2;    // 12.8 MB
    bf16x8* Bfrag1   = (bf16x8*)ws; ws += (size_t)F_HID * F_IN * 2;       //  128 KB
    bf16x8* Bfrag2   = (bf16x8*)ws; ws += (size_t)F_OUT * F_HID * 2;      //   16 KB
    int2*   rowinfo  = (int2*)ws;   ws += (size_t)N_NODES * 8;            //  400 KB
    int*    gcnt     = (int*)ws;    ws += 400 * 4;

    const int NPB = (N_EDGES + EPB - 1) / EPB;          // 196 partition blocks
    const int MT  = N_NODES / 16;                       // 3125 row tiles (exact)

    // 0) x -> fragment-order bf16 (independent of CSR build)
    {
        int n_units = MT * (F_IN / 32) * 64;            // 3.2M
        cvt_frag<F_IN><<<(n_units + 255) / 256, 256, 0, stream>>>(x, Afrag1, n_units);
    }

    // 1) CSR build (bucket partition, self-reserving fixed-capacity slots)
    hipMemsetAsync(gcnt, 0, NBUK * sizeof(int), stream);
    part_a<<<NPB, 256, 0, stream>>>(dst, src, ew, gcnt, tmp, N_EDGES);
    part_b<<<NBUK, 256, 0, stream>>>(tmp, gcnt, rowinfo, erec);

    // 2) weight prep (fragment-order bf16)
    wtrans_frag<F_IN, F_HID><<<32, 256, 0, stream>>>(W1, Bfrag1);
    wtrans_frag<F_HID, F_OUT><<<4, 256, 0, stream>>>(W2, Bfrag2);

    // 3) support1 = x @ W1 (bf16 out)
    mfma_gemm_frag<F_HID, F_IN><<<(MT + 3) / 4, 256, 0, stream>>>(Afrag1, Bfrag1, support1, MT);

    // 4) x1 = relu(spmm(support1) + b1); also emits Afrag2 (bf16 fragment order)
    spmm128<<<N_NODES, 64, 0, stream>>>(rowinfo, erec, (const unsigned*)support1, b1, x1,
                                        (unsigned*)Afrag2);

    // 5) support2 = x1 @ W2 (bf16 out)
    mfma_gemm_frag<F_OUT, F_HID><<<(MT + 3) / 4, 256, 0, stream>>>(Afrag2, Bfrag2, support2, MT);

    // 6) x2 = spmm(support2) + b2
    spmm64<<<N_NODES, 64, 0, stream>>>(rowinfo, erec, support2, b2, x2);
}

// Round 4
// 355.089 us; speedup vs baseline: 1.1854x; 1.0204x over previous
//
#include <hip/hip_runtime.h>
#include <hip/hip_bf16.h>

#define N_NODES 50000
#define N_EDGES 1600000
#define F_IN    512
#define F_HID   128
#define F_OUT   64
#define NBUK    391          // ceil(50000/128) buckets of 128 nodes
#define EPB     8192         // edges per block in bucket passes
#define CAP     4864         // per-bucket slot capacity (mean 4092, +12 sigma)

typedef short bf16x8 __attribute__((ext_vector_type(8)));
typedef float f32x4  __attribute__((ext_vector_type(4)));

__device__ __forceinline__ short f32_to_bf16(float f) {
    unsigned u = __float_as_uint(f);
    u += 0x7FFF + ((u >> 16) & 1);          // RTNE
    return (short)(u >> 16);
}
__device__ __forceinline__ float bf16_to_f32(short s) {
    return __uint_as_float(((unsigned)(unsigned short)s) << 16);
}
__device__ __forceinline__ float bf16lo(unsigned u) { return __uint_as_float(u << 16); }
__device__ __forceinline__ float bf16hi(unsigned u) { return __uint_as_float(u & 0xFFFF0000u); }

// 8x f32 -> bf16x8 via packed HW convert (RNE); 4 instrs instead of 24.
__device__ __forceinline__ bf16x8 cvt8(float4 lo, float4 hi) {
    union { unsigned u[4]; bf16x8 v; } r;
    asm("v_cvt_pk_bf16_f32 %0, %1, %2" : "=v"(r.u[0]) : "v"(lo.x), "v"(lo.y));
    asm("v_cvt_pk_bf16_f32 %0, %1, %2" : "=v"(r.u[1]) : "v"(lo.z), "v"(lo.w));
    asm("v_cvt_pk_bf16_f32 %0, %1, %2" : "=v"(r.u[2]) : "v"(hi.x), "v"(hi.y));
    asm("v_cvt_pk_bf16_f32 %0, %1, %2" : "=v"(r.u[3]) : "v"(hi.z), "v"(hi.w));
    return r.v;
}

// ---------------- CSR build: bucket partition with fixed-capacity slots ----------------

// partition edges into bucket slots (records: (dst<<16|src, w)); self-reserving cursors
__global__ __launch_bounds__(256) void part_a(const int* __restrict__ dst,
                                              const int* __restrict__ src,
                                              const float* __restrict__ w,
                                              int* __restrict__ gcnt,
                                              uint2* __restrict__ tmp, int E) {
    __shared__ int h[NBUK];
    __shared__ int base[NBUK];
    for (int i = threadIdx.x; i < NBUK; i += 256) h[i] = 0;
    __syncthreads();
    int e0 = blockIdx.x * EPB;
    int e1 = min(e0 + EPB, E);
    for (int e = e0 + threadIdx.x; e < e1; e += 256)
        atomicAdd(&h[dst[e] >> 7], 1);
    __syncthreads();
    for (int i = threadIdx.x; i < NBUK; i += 256) {
        int c = h[i];
        base[i] = c ? atomicAdd(&gcnt[i], c) : 0;
        h[i] = 0;
    }
    __syncthreads();
    for (int e = e0 + threadIdx.x; e < e1; e += 256) {
        int d = dst[e];
        int b = d >> 7;
        int off = base[b] + atomicAdd(&h[b], 1);
        if (off < CAP)
            tmp[(size_t)b * CAP + off] = make_uint2(((unsigned)d << 16) | (unsigned)src[e],
                                                    __float_as_uint(w[e]));
    }
}

// per-bucket: node histogram + prefix in LDS -> rowinfo(beg,end), bucket-local scatter
__global__ __launch_bounds__(256) void part_b(const uint2* __restrict__ tmp,
                                              const int* __restrict__ gcnt,
                                              int2* __restrict__ rowinfo,
                                              uint2* __restrict__ erec) {
    __shared__ int s[128];
    __shared__ int cur[128];
    int b = blockIdx.x, tid = threadIdx.x;
    int nb0 = b << 7;
    int r0 = b * CAP;
    int cnt_b = min(gcnt[b], CAP);
    int r1 = r0 + cnt_b;
    if (tid < 128) s[tid] = 0;
    __syncthreads();
    for (int i = r0 + tid; i < r1; i += 256)
        atomicAdd(&s[(tmp[i].x >> 16) - nb0], 1);
    __syncthreads();
    int v = (tid < 128) ? s[tid] : 0;
    #pragma unroll
    for (int off = 1; off < 128; off <<= 1) {
        int t = (tid >= off && tid < 128) ? s[tid - off] : 0;
        __syncthreads();
        if (tid < 128) s[tid] += t;
        __syncthreads();
    }
    if (tid < 128) {
        int ex = r0 + s[tid] - v;
        cur[tid] = ex;
        int node = nb0 + tid;
        if (node < N_NODES) rowinfo[node] = make_int2(ex, ex + v);
    }
    __syncthreads();
    for (int i = r0 + tid; i < r1; i += 256) {
        uint2 rec = tmp[i];
        int p = atomicAdd(&cur[(rec.x >> 16) - nb0], 1);
        erec[p] = make_uint2(rec.x & 0xFFFFu, rec.y);
    }
}

// ---------------- fragment-order conversions ----------------

// B fragment unit u = (kc*NT + nt)*64 + lane:
//   holds W[k = kc*32 + (lane>>4)*8 + j][n = nt*16 + (lane&15)]  (W is [KD][NC] row-major)
template<int KD, int NC>
__global__ void wtrans_frag(const float* __restrict__ W, bf16x8* __restrict__ Bfrag) {
    constexpr int KC = KD / 32, NT = NC / 16;
    int u = blockIdx.x * 256 + threadIdx.x;
    if (u >= KC * NT * 64) return;
    int lane = u & 63;
    int nt   = (u >> 6) % NT;
    int kc   = u / (64 * NT);
    int n = nt * 16 + (lane & 15);
    int k = kc * 32 + (lane >> 4) * 8;
    bf16x8 f;
    #pragma unroll
    for (int j = 0; j < 8; ++j) f[j] = f32_to_bf16(W[(size_t)(k + j) * NC + n]);
    Bfrag[u] = f;
}

// ---------------- MFMA GEMM, A read directly from fp32 X (in-register bf16 cvt) ----------------
// A fragment for lane: X[row = tile*16 + (lane&15)][k = kc*32 + (lane>>4)*8 .. +8]
// -> two float4 loads (fully-used 128B lines per 16-lane group), cvt8 -> MFMA A operand.

template<int NC, int KD>
__global__ __launch_bounds__(256) void mfma_gemm_x(const float* __restrict__ X,
                                                   const bf16x8* __restrict__ Bfrag,
                                                   short* __restrict__ C, int Mt) {
    constexpr int NT = NC / 16, KC = KD / 32;
    constexpr int PFA = (KC < 4) ? KC : 4;
    const int lane = threadIdx.x & 63;
    const int wave = threadIdx.x >> 6;
    const int tile = blockIdx.x * 4 + wave;
    if (tile >= Mt) return;

    const float* xp = X + (size_t)(tile * 16 + (lane & 15)) * KD + ((lane >> 4) * 8);
    const bf16x8* bp = Bfrag + lane;

    f32x4 acc[NT];
    #pragma unroll
    for (int i = 0; i < NT; ++i) acc[i] = (f32x4){0.f, 0.f, 0.f, 0.f};

    float4 alo[PFA], ahi[PFA];
    #pragma unroll
    for (int i = 0; i < PFA; ++i) {
        alo[i] = *(const float4*)(xp + i * 32);
        ahi[i] = *(const float4*)(xp + i * 32 + 4);
    }
    bf16x8 bbuf[NT];
    #pragma unroll
    for (int nt = 0; nt < NT; ++nt) bbuf[nt] = bp[(size_t)nt * 64];

    #pragma unroll
    for (int kc = 0; kc < KC; ++kc) {
        float4 lo = alo[kc % PFA], hi = ahi[kc % PFA];
        int ka = kc + PFA; if (ka > KC - 1) ka = KC - 1;
        alo[kc % PFA] = *(const float4*)(xp + ka * 32);
        ahi[kc % PFA] = *(const float4*)(xp + ka * 32 + 4);
        bf16x8 a = cvt8(lo, hi);
        int kb = (kc + 1 < KC) ? kc + 1 : kc;
        bf16x8 bnew[NT];
        #pragma unroll
        for (int nt = 0; nt < NT; ++nt) {
            bnew[nt] = bp[((size_t)kb * NT + nt) * 64];
            acc[nt] = __builtin_amdgcn_mfma_f32_16x16x32_bf16(a, bbuf[nt], acc[nt], 0, 0, 0);
        }
        #pragma unroll
        for (int nt = 0; nt < NT; ++nt) bbuf[nt] = bnew[nt];
    }

    const int lrow = lane & 15, kgrp = lane >> 4;
    #pragma unroll
    for (int nt = 0; nt < NT; ++nt) {
        #pragma unroll
        for (int r = 0; r < 4; ++r) {
            int grow = tile * 16 + kgrp * 4 + r;
            C[(size_t)grow * NC + nt * 16 + lrow] = f32_to_bf16(acc[nt][r]);
        }
    }
}

// ---------------- fragment MFMA GEMM (A already in fragment order, bf16) ----------------

template<int NC, int KD>
__global__ __launch_bounds__(256) void mfma_gemm_frag(const bf16x8* __restrict__ Afrag,
                                                      const bf16x8* __restrict__ Bfrag,
                                                      short* __restrict__ C, int Mt) {
    constexpr int NT = NC / 16, KC = KD / 32;
    constexpr int PFA = (KC < 4) ? KC : 4;
    const int lane = threadIdx.x & 63;
    const int wave = threadIdx.x >> 6;
    const int tile = blockIdx.x * 4 + wave;
    if (tile >= Mt) return;

    const bf16x8* ap = Afrag + (size_t)tile * KC * 64 + lane;
    const bf16x8* bp = Bfrag + lane;

    f32x4 acc[NT];
    #pragma unroll
    for (int i = 0; i < NT; ++i) acc[i] = (f32x4){0.f, 0.f, 0.f, 0.f};

    bf16x8 abuf[PFA];
    #pragma unroll
    for (int i = 0; i < PFA; ++i) abuf[i] = ap[(size_t)i * 64];
    bf16x8 bbuf[NT];
    #pragma unroll
    for (int nt = 0; nt < NT; ++nt) bbuf[nt] = bp[(size_t)nt * 64];

    #pragma unroll
    for (int kc = 0; kc < KC; ++kc) {
        bf16x8 a = abuf[kc % PFA];
        int ka = kc + PFA; if (ka > KC - 1) ka = KC - 1;
        abuf[kc % PFA] = ap[(size_t)ka * 64];
        int kb = (kc + 1 < KC) ? kc + 1 : kc;
        bf16x8 bnew[NT];
        #pragma unroll
        for (int nt = 0; nt < NT; ++nt) {
            bnew[nt] = bp[((size_t)kb * NT + nt) * 64];
            acc[nt] = __builtin_amdgcn_mfma_f32_16x16x32_bf16(a, bbuf[nt], acc[nt], 0, 0, 0);
        }
        #pragma unroll
        for (int nt = 0; nt < NT; ++nt) bbuf[nt] = bnew[nt];
    }

    const int lrow = lane & 15, kgrp = lane >> 4;
    #pragma unroll
    for (int nt = 0; nt < NT; ++nt) {
        #pragma unroll
        for (int r = 0; r < 4; ++r) {
            int grow = tile * 16 + kgrp * 4 + r;
            C[(size_t)grow * NC + nt * 16 + lrow] = f32_to_bf16(acc[nt][r]);
        }
    }
}

// ---------------- SpMM gather ----------------

// F=128: one wave per node. 8-wide UNMASKED main loop, software-pipelined:
// erec batch for iteration i+1 issues while iteration i's feat gathers are in
// flight. Tails: 4-wide then scalar (no per-edge compares anywhere).
// lane t owns feats (2t, 2t+1); frag uint slot:
//   unit = (tile*4 + t/16)*64 + ((t>>2)&3)*16 + (d&15), uint index = unit*4 + (t&3)
__global__ __launch_bounds__(64) void spmm128(const int2* __restrict__ rowinfo,
                                              const uint2* __restrict__ erec,
                                              const unsigned* __restrict__ featu,
                                              const float* __restrict__ bias,
                                              float* __restrict__ out,
                                              unsigned* __restrict__ afrag2u) {
    int d = blockIdx.x, tid = threadIdx.x;
    int2 ri = rowinfo[d];
    int beg = ri.x, end = ri.y;
    float a0 = 0.f, a1 = 0.f;
    const unsigned* fp = featu + tid;
    int e = beg;
    if (end - beg >= 8) {
        uint2 r[8];
        #pragma unroll
        for (int j = 0; j < 8; ++j) r[j] = erec[e + j];
        for (; e + 16 <= end; e += 8) {
            unsigned f[8];
            #pragma unroll
            for (int j = 0; j < 8; ++j) f[j] = fp[r[j].x * 64u];
            uint2 rn[8];
            #pragma unroll
            for (int j = 0; j < 8; ++j) rn[j] = erec[e + 8 + j];
            #pragma unroll
            for (int j = 0; j < 8; ++j) {
                float w = __uint_as_float(r[j].y);
                a0 += w * bf16lo(f[j]);
                a1 += w * bf16hi(f[j]);
            }
            #pragma unroll
            for (int j = 0; j < 8; ++j) r[j] = rn[j];
        }
        {   // drain: last full batch, no prefetch
            unsigned f[8];
            #pragma unroll
            for (int j = 0; j < 8; ++j) f[j] = fp[r[j].x * 64u];
            #pragma unroll
            for (int j = 0; j < 8; ++j) {
                float w = __uint_as_float(r[j].y);
                a0 += w * bf16lo(f[j]);
                a1 += w * bf16hi(f[j]);
            }
            e += 8;
        }
    }
    for (; e + 4 <= end; e += 4) {
        uint2 r0 = erec[e], r1 = erec[e + 1], r2 = erec[e + 2], r3 = erec[e + 3];
        unsigned f0 = fp[r0.x * 64u];
        unsigned f1 = fp[r1.x * 64u];
        unsigned f2 = fp[r2.x * 64u];
        unsigned f3 = fp[r3.x * 64u];
        float w0 = __uint_as_float(r0.y), w1 = __uint_as_float(r1.y);
        float w2 = __uint_as_float(r2.y), w3 = __uint_as_float(r3.y);
        a0 += w0 * bf16lo(f0); a1 += w0 * bf16hi(f0);
        a0 += w1 * bf16lo(f1); a1 += w1 * bf16hi(f1);
        a0 += w2 * bf16lo(f2); a1 += w2 * bf16hi(f2);
        a0 += w3 * bf16lo(f3); a1 += w3 * bf16hi(f3);
    }
    for (; e < end; ++e) {
        uint2 r = erec[e];
        unsigned f = fp[r.x * 64u];
        float w = __uint_as_float(r.y);
        a0 += w * bf16lo(f); a1 += w * bf16hi(f);
    }
    float ox = fmaxf(a0 + bias[2 * tid], 0.f);
    float oy = fmaxf(a1 + bias[2 * tid + 1], 0.f);
    *(float2*)&out[(size_t)d * 128 + 2 * tid] = make_float2(ox, oy);
    unsigned packed = (unsigned)(unsigned short)f32_to_bf16(ox) |
                      ((unsigned)(unsigned short)f32_to_bf16(oy) << 16);
    int unit = ((d >> 4) * 4 + (tid >> 4)) * 64 + ((tid >> 2) & 3) * 16 + (d & 15);
    afrag2u[unit * 4 + (tid & 3)] = packed;
}

// F=64: one wave per node, same pipelined 8-wide structure.
__global__ __launch_bounds__(64) void spmm64(const int2* __restrict__ rowinfo,
                                             const uint2* __restrict__ erec,
                                             const short* __restrict__ feat,
                                             const float* __restrict__ bias,
                                             float* __restrict__ out) {
    int d = blockIdx.x, tid = threadIdx.x;
    int2 ri = rowinfo[d];
    int beg = ri.x, end = ri.y;
    float acc = 0.f;
    const short* fp = feat + tid;
    int e = beg;
    if (end - beg >= 8) {
        uint2 r[8];
        #pragma unroll
        for (int j = 0; j < 8; ++j) r[j] = erec[e + j];
        for (; e + 16 <= end; e += 8) {
            float f[8];
            #pragma unroll
            for (int j = 0; j < 8; ++j) f[j] = bf16_to_f32(fp[r[j].x * 64u]);
            uint2 rn[8];
            #pragma unroll
            for (int j = 0; j < 8; ++j) rn[j] = erec[e + 8 + j];
            #pragma unroll
            for (int j = 0; j < 8; ++j) acc += __uint_as_float(r[j].y) * f[j];
            #pragma unroll
            for (int j = 0; j < 8; ++j) r[j] = rn[j];
        }
        {
            float f[8];
            #pragma unroll
            for (int j = 0; j < 8; ++j) f[j] = bf16_to_f32(fp[r[j].x * 64u]);
            #pragma unroll
            for (int j = 0; j < 8; ++j) acc += __uint_as_float(r[j].y) * f[j];
            e += 8;
        }
    }
    for (; e + 4 <= end; e += 4) {
        uint2 r0 = erec[e], r1 = erec[e + 1], r2 = erec[e + 2], r3 = erec[e + 3];
        float f0 = bf16_to_f32(fp[r0.x * 64u]);
        float f1 = bf16_to_f32(fp[r1.x * 64u]);
        float f2 = bf16_to_f32(fp[r2.x * 64u]);
        float f3 = bf16_to_f32(fp[r3.x * 64u]);
        acc += __uint_as_float(r0.y) * f0;
        acc += __uint_as_float(r1.y) * f1;
        acc += __uint_as_float(r2.y) * f2;
        acc += __uint_as_float(r3.y) * f3;
    }
    for (; e < end; ++e) {
        uint2 r = erec[e];
        acc += __uint_as_float(r.y) * bf16_to_f32(fp[r.x * 64u]);
    }
    out[(size_t)d * 64 + tid] = acc + bias[tid];
}

// ---------------- launch ----------------

extern "C" void kernel_launch(void* const* d_in, const int* in_sizes, int n_in,
                              void* d_out, int out_size, void* d_ws, size_t ws_size,
                              hipStream_t stream) {
    const float* x  = (const float*)d_in[0];
    const int*   ei = (const int*)d_in[1];
    const float* ew = (const float*)d_in[2];
    const float* W1 = (const float*)d_in[3];
    const float* b1 = (const float*)d_in[4];
    const float* W2 = (const float*)d_in[5];
    const float* b2 = (const float*)d_in[6];

    const int* dst = ei;
    const int* src = ei + N_EDGES;

    float* x1 = (float*)d_out;                          // [50000,128] fp32
    float* x2 = x1 + (size_t)N_NODES * F_HID;           // [50000,64]  fp32

    char* ws = (char*)d_ws;
    uint2*  erec     = (uint2*)ws;  ws += (size_t)NBUK * CAP * 8;         // 15.2 MB (slotted)
    uint2*  tmp      = (uint2*)ws;  ws += (size_t)NBUK * CAP * 8;         // 15.2 MB (slotted)
    short*  support1 = (short*)ws;  ws += (size_t)N_NODES * F_HID * 2;    // 12.8 MB
    short*  support2 = (short*)ws;  ws += (size_t)N_NODES * F_OUT * 2;    //  6.4 MB
    bf16x8* Afrag2   = (bf16x8*)ws; ws += (size_t)N_NODES * F_HID * 2;    // 12.8 MB
    bf16x8* Bfrag1   = (bf16x8*)ws; ws += (size_t)F_HID * F_IN * 2;       //  128 KB
    bf16x8* Bfrag2   = (bf16x8*)ws; ws += (size_t)F_OUT * F_HID * 2;      //   16 KB
    int2*   rowinfo  = (int2*)ws;   ws += (size_t)N_NODES * 8;            //  400 KB
    int*    gcnt     = (int*)ws;    ws += 400 * 4;

    const int NPB = (N_EDGES + EPB - 1) / EPB;          // 196 partition blocks
    const int MT  = N_NODES / 16;                       // 3125 row tiles (exact)

    // 1) CSR build (bucket partition, self-reserving fixed-capacity slots)
    hipMemsetAsync(gcnt, 0, NBUK * sizeof(int), stream);
    part_a<<<NPB, 256, 0, stream>>>(dst, src, ew, gcnt, tmp, N_EDGES);
    part_b<<<NBUK, 256, 0, stream>>>(tmp, gcnt, rowinfo, erec);

    // 2) weight prep (fragment-order bf16)
    wtrans_frag<F_IN, F_HID><<<32, 256, 0, stream>>>(W1, Bfrag1);
    wtrans_frag<F_HID, F_OUT><<<4, 256, 0, stream>>>(W2, Bfrag2);

    // 3) support1 = x @ W1 (bf16 out) — A read directly from fp32 x, cvt in-register
    mfma_gemm_x<F_HID, F_IN><<<(MT + 3) / 4, 256, 0, stream>>>(x, Bfrag1, support1, MT);

    // 4) x1 = relu(spmm(support1) + b1); also emits Afrag2 (bf16 fragment order)
    spmm128<<<N_NODES, 64, 0, stream>>>(rowinfo, erec, (const unsigned*)support1, b1, x1,
                                        (unsigned*)Afrag2);

    // 5) support2 = x1 @ W2 (bf16 out)
    mfma_gemm_frag<F_OUT, F_HID><<<(MT + 3) / 4, 256, 0, stream>>>(Afrag2, Bfrag2, support2, MT);

    // 6) x2 = spmm(support2) + b2
    spmm64<<<N_NODES, 64, 0, stream>>>(rowinfo, erec, support2, b2, x2);
}